// Round 2
// baseline (182.675 us; speedup 1.0000x reference)
//
#include <hip/hip_runtime.h>
#include <hip/hip_bf16.h>

#define NROWS 8192
#define KDIM  256
#define NT    64                  // NROWS / 128
#define NBLK  (NT * (NT + 1) / 2) // 2080 upper-triangular 128x128 tiles

typedef __attribute__((ext_vector_type(8))) __bf16 bf16x8;
typedef __attribute__((ext_vector_type(4))) float f32x4;

// ---------------------------------------------------------------------------
// Kernel 1: fp32 -> bf16 convert + per-row sum of squares; block 0 zeroes the
// two global accumulators (stream order guarantees visibility to pair_kernel).
// ---------------------------------------------------------------------------
__global__ void prep_kernel(const float* __restrict__ samples,
                            __hip_bfloat16* __restrict__ sbf,
                            float* __restrict__ sq,
                            float* __restrict__ accg) {
  int row = blockIdx.x, t = threadIdx.x;           // 256 threads = 1 row
  size_t idx = (size_t)row * KDIM + t;
  float v = samples[idx];
  sbf[idx] = __float2bfloat16(v);
  float p = v * v;
#pragma unroll
  for (int off = 32; off; off >>= 1) p += __shfl_down(p, off);
  __shared__ float wsum[4];
  int lane = t & 63, w = t >> 6;
  if (lane == 0) wsum[w] = p;
  __syncthreads();
  if (t == 0) sq[row] = wsum[0] + wsum[1] + wsum[2] + wsum[3];
  if (row == 0 && t < 2) accg[t] = 0.0f;
}

// ---------------------------------------------------------------------------
// Kernel 2: fused Gram-tile -> S_ij -> masked sums. One block = one 128x128
// tile (bi<=bj); 4 waves, each a 64x64 quadrant of 4x4 16x16x32 MFMAs.
// NO LDS staging of A/B: fragments load straight from global (L2-resident,
// 16 rows x 64B contiguous per wave-load) -> zero hot-loop barriers.
// ---------------------------------------------------------------------------
__global__ __launch_bounds__(256) void pair_kernel(
    const __bf16* __restrict__ sbf, const float* __restrict__ sq,
    const int* __restrict__ labels, float* __restrict__ accg) {

  __shared__ float sqA[128], sqB[128];
  __shared__ int   laA[128], laB[128];
  __shared__ float red[8];

  int t = threadIdx.x;
  int lane = t & 63;
  int w = t >> 6;
  int wm = w >> 1, wn = w & 1;

  // decode triangular block index b -> (bi, bj), bi <= bj
  int b = blockIdx.x;
  float disc = (2.0f * NT + 1.0f) * (2.0f * NT + 1.0f) - 8.0f * (float)b;
  int bi = (int)(((2.0f * NT + 1.0f) - sqrtf(disc)) * 0.5f);
  if (bi < 0) bi = 0;
  if (bi > NT - 1) bi = NT - 1;
  while (bi > 0 && (bi * NT - bi * (bi - 1) / 2) > b) --bi;
  while (((bi + 1) * NT - (bi + 1) * bi / 2) <= b) ++bi;
  int bj = bi + (b - (bi * NT - bi * (bi - 1) / 2));

  int rowA0 = bi * 128, rowB0 = bj * 128;

  // stage sq/labels; consumed only after the post-MFMA barrier
  if (t < 128) { sqA[t] = sq[rowA0 + t]; laA[t] = labels[rowA0 + t]; }
  else { int u = t - 128; sqB[u] = sq[rowB0 + u]; laB[u] = labels[rowB0 + u]; }

  f32x4 acc[4][4];
#pragma unroll
  for (int i = 0; i < 4; i++)
#pragma unroll
    for (int j = 0; j < 4; j++) acc[i][j] = (f32x4){0.f, 0.f, 0.f, 0.f};

  int r = lane & 15;    // fragment row within 16
  int ko = lane >> 4;   // k-quad: k offset = ko*8

  const __bf16* Ab = sbf + (size_t)(rowA0 + wm * 64 + r) * KDIM + ko * 8;
  const __bf16* Bb = sbf + (size_t)(rowB0 + wn * 64 + r) * KDIM + ko * 8;

#pragma unroll
  for (int kc = 0; kc < KDIM / 32; ++kc) {
    bf16x8 af[4], bfr[4];
#pragma unroll
    for (int i = 0; i < 4; i++) {
      af[i]  = *(const bf16x8*)(Ab + (size_t)i * 16 * KDIM + kc * 32);
      bfr[i] = *(const bf16x8*)(Bb + (size_t)i * 16 * KDIM + kc * 32);
    }
#pragma unroll
    for (int i = 0; i < 4; i++)
#pragma unroll
      for (int j = 0; j < 4; j++)
        acc[i][j] = __builtin_amdgcn_mfma_f32_16x16x32_bf16(af[i], bfr[j],
                                                            acc[i][j], 0, 0, 0);
  }

  __syncthreads();  // sq/label staging visible to all

  // epilogue: gram -> S -> masked partial sums
  // C/D layout: col = lane&15 (n), row = (lane>>4)*4 + reg (m)
  float s1 = 0.f, s2 = 0.f;
  int q4 = (lane >> 4) * 4;
  int cl = lane & 15;
#pragma unroll
  for (int j = 0; j < 4; j++) {
    int lc = wn * 64 + j * 16 + cl;
    float sqb = sqB[lc];
    int   lb  = laB[lc];
#pragma unroll
    for (int i = 0; i < 4; i++) {
#pragma unroll
      for (int q = 0; q < 4; q++) {
        int lr = wm * 64 + i * 16 + q4 + q;
        float S = (sqA[lr] + sqb - 2.0f * acc[i][j][q]) * (1.0f / 256.0f);
        if (laA[lr] == lb) s1 += S;
        else               s2 += fmaxf(0.f, 1.f - S);
      }
    }
  }
#pragma unroll
  for (int off = 32; off; off >>= 1) {
    s1 += __shfl_down(s1, off);
    s2 += __shfl_down(s2, off);
  }
  if (lane == 0) { red[w] = s1; red[4 + w] = s2; }
  __syncthreads();
  if (t == 0) {
    float wt = (bi == bj) ? 1.0f : 2.0f;  // off-diagonal tiles count twice
    atomicAdd(&accg[0], (red[0] + red[1] + red[2] + red[3]) * wt);
    atomicAdd(&accg[1], (red[4] + red[5] + red[6] + red[7]) * wt);
  }
}

// ---------------------------------------------------------------------------
// Kernel 3: final scalar
// ---------------------------------------------------------------------------
__global__ void finalize_kernel(const float* __restrict__ accg,
                                float* __restrict__ out) {
  out[0] = 10.0f * (accg[0] + accg[1]) *
           (1.0f / ((float)NROWS * (float)NROWS));
}

extern "C" void kernel_launch(void* const* d_in, const int* in_sizes, int n_in,
                              void* d_out, int out_size, void* d_ws,
                              size_t ws_size, hipStream_t stream) {
  // inputs: 0=merged (unused), 1=input1 (unused), 2=samples, 3=labels
  const float* samples = (const float*)d_in[2];
  const int*   labels  = (const int*)d_in[3];

  char* ws = (char*)d_ws;
  __hip_bfloat16* sbf = (__hip_bfloat16*)ws;                      // 4 MiB
  float* sq   = (float*)(ws + (size_t)NROWS * KDIM * 2);          // 32 KiB
  float* accg = (float*)(ws + (size_t)NROWS * KDIM * 2 + NROWS * 4); // 8 B
  float* out  = (float*)d_out;

  prep_kernel<<<NROWS, 256, 0, stream>>>(samples, sbf, sq, accg);
  pair_kernel<<<NBLK, 256, 0, stream>>>((const __bf16*)sbf, sq, labels, accg);
  finalize_kernel<<<1, 1, 0, stream>>>(accg, out);
}

// Round 3
// 162.899 us; speedup vs baseline: 1.1214x; 1.1214x over previous
//
#include <hip/hip_runtime.h>
#include <hip/hip_bf16.h>

#define NROWS 8192
#define KDIM  256
#define NT    64                  // NROWS / 128
#define NBLK  (NT * (NT + 1) / 2) // 2080 upper-triangular 128x128 tiles

typedef __attribute__((ext_vector_type(4))) float f32x4;

// async global->LDS, 16B per lane; LDS dest is wave-uniform base + lane*16
#define GLD(gp, lp)                                                            \
  __builtin_amdgcn_global_load_lds(                                            \
      (const __attribute__((address_space(1))) void*)(gp),                     \
      (__attribute__((address_space(3))) void*)(lp), 16, 0, 0)

// ---------------------------------------------------------------------------
// Kernel 1: fp32 -> fp8 e4m3 (OCP) convert + per-row sum of squares (fp32).
// 128 threads = 1 row (2 elems/thread, packed fp8 store). Block 0 zeroes the
// global accumulators (stream order guarantees visibility to pair_kernel).
// ---------------------------------------------------------------------------
__global__ void prep_kernel(const float* __restrict__ samples,
                            unsigned char* __restrict__ sf8,
                            float* __restrict__ sq,
                            float* __restrict__ accg) {
  int row = blockIdx.x, t = threadIdx.x;  // t in [0,128)
  float2 v2 = ((const float2*)samples)[(size_t)row * 128 + t];
  int pk = __builtin_amdgcn_cvt_pk_fp8_f32(v2.x, v2.y, 0, false);
  ((unsigned short*)sf8)[(size_t)row * 128 + t] = (unsigned short)(pk & 0xffff);
  float p = v2.x * v2.x + v2.y * v2.y;
#pragma unroll
  for (int off = 32; off; off >>= 1) p += __shfl_down(p, off);
  __shared__ float ws2[2];
  if ((t & 63) == 0) ws2[t >> 6] = p;
  __syncthreads();
  if (t == 0) sq[row] = ws2[0] + ws2[1];
  if (row == 0 && t < 2) accg[t] = 0.0f;
}

// ---------------------------------------------------------------------------
// Kernel 2: fused Gram-tile (fp8 MFMA) -> S_ij -> masked sums.
// One block = one 128x128 tile (bi<=bj). FULL K=256 staged in LDS ONCE
// (A 32KB + B 32KB fp8 -> 2 blocks/CU), so the MFMA phase has ZERO barriers.
// LDS rows are XOR-16B swizzled (phys_chunk = log_chunk ^ (row&15)) so the
// ds_read_b64 fragment loads are <=4-way bank conflicted instead of 16-way;
// staging applies the same swizzle on the GLOBAL side (lds base stays
// wave-uniform as global_load_lds requires).
// ---------------------------------------------------------------------------
__global__ __launch_bounds__(256, 2) void pair_kernel(
    const unsigned char* __restrict__ sf8, const float* __restrict__ sq,
    const int* __restrict__ labels, float* __restrict__ accg) {

  __shared__ __align__(16) unsigned char As[128 * 256];
  __shared__ __align__(16) unsigned char Bs[128 * 256];
  __shared__ float sqA[128], sqB[128];
  __shared__ int   laA[128], laB[128];
  __shared__ float red[8];

  int t = threadIdx.x;
  int lane = t & 63;
  int w = t >> 6;
  int wm = w >> 1, wn = w & 1;

  // decode triangular block index b -> (bi, bj), bi <= bj
  int b = blockIdx.x;
  float disc = (2.0f * NT + 1.0f) * (2.0f * NT + 1.0f) - 8.0f * (float)b;
  int bi = (int)(((2.0f * NT + 1.0f) - sqrtf(disc)) * 0.5f);
  if (bi < 0) bi = 0;
  if (bi > NT - 1) bi = NT - 1;
  while (bi > 0 && (bi * NT - bi * (bi - 1) / 2) > b) --bi;
  while (((bi + 1) * NT - (bi + 1) * bi / 2) <= b) ++bi;
  int bj = bi + (b - (bi * NT - bi * (bi - 1) / 2));

  int rowA0 = bi * 128, rowB0 = bj * 128;

  // stage sq/labels (consumed after the one barrier)
  if (t < 128) { sqA[t] = sq[rowA0 + t]; laA[t] = labels[rowA0 + t]; }
  else { int u = t - 128; sqB[u] = sq[rowB0 + u]; laB[u] = labels[rowB0 + u]; }

  // ---- one-shot full-K staging: 16 async wave-loads, no VGPR round-trip ----
  {
    int lr = lane >> 4;   // row within 4-row region
    int pc = lane & 15;   // PHYSICAL 16B chunk this lane fills
#pragma unroll
    for (int p = 0; p < 8; ++p) {
      int region = p * 4 + w;           // 32 regions x 1KB (4 rows each)
      int r = region * 4 + lr;          // tile row 0..127
      int c = pc ^ (r & 15);            // logical (global) chunk
      GLD(sf8 + (size_t)(rowA0 + r) * KDIM + c * 16, &As[region * 1024]);
      GLD(sf8 + (size_t)(rowB0 + r) * KDIM + c * 16, &Bs[region * 1024]);
    }
  }

  f32x4 acc[4][4];
#pragma unroll
  for (int i = 0; i < 4; i++)
#pragma unroll
    for (int j = 0; j < 4; j++) acc[i][j] = (f32x4){0.f, 0.f, 0.f, 0.f};

  __syncthreads();  // drains GLD (vmcnt) + covers sq/label staging

  // ---- barrier-free MFMA phase: 64 ds_read_b64 + 128 MFMA per wave ----
  int r = lane & 15;          // fragment row within 16
  int kq = (lane >> 4) >> 1;  // which 16B chunk-half pair
  int hf = ((lane >> 4) & 1) * 8;
#pragma unroll
  for (int kc = 0; kc < 8; ++kc) {
    long af[4], bfr[4];
#pragma unroll
    for (int i = 0; i < 4; i++) {
      int m = wm * 64 + i * 16 + r;
      af[i]  = *(const long*)(&As[m * 256 + (((kc * 2 + kq) ^ r) * 16) + hf]);
      int n = wn * 64 + i * 16 + r;
      bfr[i] = *(const long*)(&Bs[n * 256 + (((kc * 2 + kq) ^ r) * 16) + hf]);
    }
#pragma unroll
    for (int i = 0; i < 4; i++)
#pragma unroll
      for (int j = 0; j < 4; j++)
        acc[i][j] = __builtin_amdgcn_mfma_f32_16x16x32_fp8_fp8(
            af[i], bfr[j], acc[i][j], 0, 0, 0);
  }

  // epilogue: gram -> S -> masked partial sums
  // C/D layout: col = lane&15 (n), row = (lane>>4)*4 + reg (m)
  float s1 = 0.f, s2 = 0.f;
  int q4 = (lane >> 4) * 4;
  int cl = lane & 15;
#pragma unroll
  for (int j = 0; j < 4; j++) {
    int lc = wn * 64 + j * 16 + cl;
    float sqb = sqB[lc];
    int   lb  = laB[lc];
#pragma unroll
    for (int i = 0; i < 4; i++) {
#pragma unroll
      for (int q = 0; q < 4; q++) {
        int lr2 = wm * 64 + i * 16 + q4 + q;
        float S = (sqA[lr2] + sqb - 2.0f * acc[i][j][q]) * (1.0f / 256.0f);
        if (laA[lr2] == lb) s1 += S;
        else               s2 += fmaxf(0.f, 1.f - S);
      }
    }
  }
#pragma unroll
  for (int off = 32; off; off >>= 1) {
    s1 += __shfl_down(s1, off);
    s2 += __shfl_down(s2, off);
  }
  if (lane == 0) { red[w] = s1; red[4 + w] = s2; }
  __syncthreads();
  if (t == 0) {
    float wt = (bi == bj) ? 1.0f : 2.0f;  // off-diagonal tiles count twice
    atomicAdd(&accg[0], (red[0] + red[1] + red[2] + red[3]) * wt);
    atomicAdd(&accg[1], (red[4] + red[5] + red[6] + red[7]) * wt);
  }
}

// ---------------------------------------------------------------------------
// Kernel 3: final scalar
// ---------------------------------------------------------------------------
__global__ void finalize_kernel(const float* __restrict__ accg,
                                float* __restrict__ out) {
  out[0] = 10.0f * (accg[0] + accg[1]) *
           (1.0f / ((float)NROWS * (float)NROWS));
}

extern "C" void kernel_launch(void* const* d_in, const int* in_sizes, int n_in,
                              void* d_out, int out_size, void* d_ws,
                              size_t ws_size, hipStream_t stream) {
  // inputs: 0=merged (unused), 1=input1 (unused), 2=samples, 3=labels
  const float* samples = (const float*)d_in[2];
  const int*   labels  = (const int*)d_in[3];

  char* ws = (char*)d_ws;
  unsigned char* sf8 = (unsigned char*)ws;                        // 2 MiB fp8
  float* sq   = (float*)(ws + (size_t)NROWS * KDIM);              // 32 KiB
  float* accg = (float*)(ws + (size_t)NROWS * KDIM + NROWS * 4);  // 8 B
  float* out  = (float*)d_out;

  prep_kernel<<<NROWS, 128, 0, stream>>>(samples, sf8, sq, accg);
  pair_kernel<<<NBLK, 256, 0, stream>>>(sf8, sq, labels, accg);
  finalize_kernel<<<1, 1, 0, stream>>>(accg, out);
}

// Round 4
// 136.110 us; speedup vs baseline: 1.3421x; 1.1968x over previous
//
#include <hip/hip_runtime.h>
#include <hip/hip_bf16.h>

#define NROWS 8192
#define KDIM  256
#define NT    64                  // NROWS / 128
#define NBLK  (NT * (NT + 1) / 2) // 2080 upper-triangular 128x128 tiles
#define GRID  256                 // persistent blocks; 8-9 tiles each

typedef __attribute__((ext_vector_type(4))) float f32x4;

// async global->LDS, 16B per lane; LDS dest is wave-uniform base + lane*16
#define GLD(gp, lp)                                                            \
  __builtin_amdgcn_global_load_lds(                                            \
      (const __attribute__((address_space(1))) void*)(gp),                     \
      (__attribute__((address_space(3))) void*)(lp), 16, 0, 0)

// ---------------------------------------------------------------------------
// Kernel 1: fp32 -> fp8 e4m3 (OCP) convert + per-row sum of squares (fp32).
// ---------------------------------------------------------------------------
__global__ void prep_kernel(const float* __restrict__ samples,
                            unsigned char* __restrict__ sf8,
                            float* __restrict__ sq,
                            float* __restrict__ accg) {
  int row = blockIdx.x, t = threadIdx.x;  // t in [0,128)
  float2 v2 = ((const float2*)samples)[(size_t)row * 128 + t];
  int pk = __builtin_amdgcn_cvt_pk_fp8_f32(v2.x, v2.y, 0, false);
  ((unsigned short*)sf8)[(size_t)row * 128 + t] = (unsigned short)(pk & 0xffff);
  float p = v2.x * v2.x + v2.y * v2.y;
#pragma unroll
  for (int off = 32; off; off >>= 1) p += __shfl_down(p, off);
  __shared__ float ws2[2];
  if ((t & 63) == 0) ws2[t >> 6] = p;
  __syncthreads();
  if (t == 0) sq[row] = ws2[0] + ws2[1];
  if (row == 0 && t < 2) accg[t] = 0.0f;
}

// decode triangular block index b -> (bi, bj), bi <= bj  (verified absmax 0.0)
__device__ inline void decode_tile(int b, int& bi, int& bj) {
  float disc = (2.0f * NT + 1.0f) * (2.0f * NT + 1.0f) - 8.0f * (float)b;
  bi = (int)(((2.0f * NT + 1.0f) - sqrtf(disc)) * 0.5f);
  if (bi < 0) bi = 0;
  if (bi > NT - 1) bi = NT - 1;
  while (bi > 0 && (bi * NT - bi * (bi - 1) / 2) > b) --bi;
  while (((bi + 1) * NT - (bi + 1) * bi / 2) <= b) ++bi;
  bj = bi + (b - (bi * NT - bi * (bi - 1) / 2));
}

// ---------------------------------------------------------------------------
// Kernel 2: persistent blocks, tile-level double-buffered fp8 Gram tiles.
// 512 threads = 8 waves, each wave a 32x64 quadrant (2x4 grid of 16x16x32).
// Per tile: ONE barrier; next tile's 64KB prefetch (async GLD) flies behind
// the MFMA phase. Loss terms accumulate in registers across tiles; one
// reduction + 2 atomics per block at the very end.
// ---------------------------------------------------------------------------
__global__ __launch_bounds__(512, 1) void pair_kernel(
    const unsigned char* __restrict__ sf8, const float* __restrict__ sq,
    const int* __restrict__ labels, float* __restrict__ accg) {

  __shared__ __align__(16) unsigned char As[2][128 * 256];
  __shared__ __align__(16) unsigned char Bs[2][128 * 256];
  __shared__ float red[16];

  int t = threadIdx.x;
  int lane = t & 63;
  int w = t >> 6;            // 0..7
  int wm = w >> 1, wn = w & 1;  // wave quadrant: rows wm*32+, cols wn*64+
  int lr = lane >> 4, pc = lane & 15;  // staging: row-in-region, phys chunk
  int r = lane & 15;                    // fragment row within 16
  int kq = (lane >> 4) >> 1;
  int hf = ((lane >> 4) & 1) * 8;
  int q4 = (lane >> 4) * 4;
  int cl = lane & 15;

  float s1t = 0.f, s2t = 0.f;

  // stage tile (bi,bj) into buffer `buf`: 32 regions x 1KB per matrix,
  // XOR-16B swizzle applied on the GLOBAL side (LDS base stays wave-uniform)
  auto stage = [&](int bi_, int bj_, int buf) {
    int rA = bi_ * 128, rB = bj_ * 128;
#pragma unroll
    for (int p = 0; p < 4; ++p) {
      int region = p * 8 + w;
      int rr = region * 4 + lr;
      int c = pc ^ (rr & 15);
      GLD(sf8 + (size_t)(rA + rr) * KDIM + c * 16, &As[buf][region * 1024]);
      GLD(sf8 + (size_t)(rB + rr) * KDIM + c * 16, &Bs[buf][region * 1024]);
    }
  };

  int tile = blockIdx.x;
  int bi, bj;
  decode_tile(tile, bi, bj);
  stage(bi, bj, 0);
  int cur = 0;

  while (tile < NBLK) {
    int ntile = tile + GRID;
    int nbi = 0, nbj = 0;
    bool have_next = ntile < NBLK;
    if (have_next) decode_tile(ntile, nbi, nbj);

    __syncthreads();  // buf[cur] staging complete (vmcnt drain at barrier)

    // epilogue scalars for CUR tile -- issued BEFORE the prefetch GLDs so
    // their (in-order) vmcnt waits don't force prefetch completion
    int rowA0 = bi * 128, rowB0 = bj * 128;
    float sqa[8], sqb[4];
    int laa[8], lab[4];
#pragma unroll
    for (int i = 0; i < 2; i++)
#pragma unroll
      for (int q = 0; q < 4; q++) {
        int gr = rowA0 + wm * 32 + i * 16 + q4 + q;
        sqa[i * 4 + q] = sq[gr];
        laa[i * 4 + q] = labels[gr];
      }
#pragma unroll
    for (int j = 0; j < 4; j++) {
      int gc = rowB0 + wn * 64 + j * 16 + cl;
      sqb[j] = sq[gc];
      lab[j] = labels[gc];
    }

    if (have_next) stage(nbi, nbj, cur ^ 1);  // async prefetch, other buffer

    // ---- barrier-free MFMA phase on buf[cur] ----
    f32x4 acc[2][4];
#pragma unroll
    for (int i = 0; i < 2; i++)
#pragma unroll
      for (int j = 0; j < 4; j++) acc[i][j] = (f32x4){0.f, 0.f, 0.f, 0.f};

#pragma unroll
    for (int kc = 0; kc < 8; ++kc) {
      long af[2], bfr[4];
#pragma unroll
      for (int i = 0; i < 2; i++) {
        int m = wm * 32 + i * 16 + r;
        af[i] = *(const long*)(&As[cur][m * 256 + (((kc * 2 + kq) ^ r) * 16) + hf]);
      }
#pragma unroll
      for (int j = 0; j < 4; j++) {
        int n = wn * 64 + j * 16 + r;
        bfr[j] = *(const long*)(&Bs[cur][n * 256 + (((kc * 2 + kq) ^ r) * 16) + hf]);
      }
#pragma unroll
      for (int i = 0; i < 2; i++)
#pragma unroll
        for (int j = 0; j < 4; j++)
          acc[i][j] = __builtin_amdgcn_mfma_f32_16x16x32_fp8_fp8(
              af[i], bfr[j], acc[i][j], 0, 0, 0);
    }

    // ---- epilogue: gram -> S -> masked sums, accumulate in registers ----
    // C/D layout: col = lane&15 (n), row = (lane>>4)*4 + reg (m)
    float s1 = 0.f, s2 = 0.f;
#pragma unroll
    for (int j = 0; j < 4; j++) {
#pragma unroll
      for (int i = 0; i < 2; i++) {
#pragma unroll
        for (int q = 0; q < 4; q++) {
          float S = (sqa[i * 4 + q] + sqb[j] - 2.0f * acc[i][j][q]) *
                    (1.0f / 256.0f);
          if (laa[i * 4 + q] == lab[j]) s1 += S;
          else                          s2 += fmaxf(0.f, 1.f - S);
        }
      }
    }
    float wt = (bi == bj) ? 1.0f : 2.0f;  // off-diagonal tiles count twice
    s1t += wt * s1;
    s2t += wt * s2;

    tile = ntile; bi = nbi; bj = nbj; cur ^= 1;
  }

  // ---- once per block: reduce 8 waves, 2 atomics ----
#pragma unroll
  for (int off = 32; off; off >>= 1) {
    s1t += __shfl_down(s1t, off);
    s2t += __shfl_down(s2t, off);
  }
  if (lane == 0) { red[w] = s1t; red[8 + w] = s2t; }
  __syncthreads();
  if (t == 0) {
    float a = 0.f, b2 = 0.f;
#pragma unroll
    for (int k = 0; k < 8; k++) { a += red[k]; b2 += red[8 + k]; }
    atomicAdd(&accg[0], a);
    atomicAdd(&accg[1], b2);
  }
}

// ---------------------------------------------------------------------------
// Kernel 3: final scalar
// ---------------------------------------------------------------------------
__global__ void finalize_kernel(const float* __restrict__ accg,
                                float* __restrict__ out) {
  out[0] = 10.0f * (accg[0] + accg[1]) *
           (1.0f / ((float)NROWS * (float)NROWS));
}

extern "C" void kernel_launch(void* const* d_in, const int* in_sizes, int n_in,
                              void* d_out, int out_size, void* d_ws,
                              size_t ws_size, hipStream_t stream) {
  // inputs: 0=merged (unused), 1=input1 (unused), 2=samples, 3=labels
  const float* samples = (const float*)d_in[2];
  const int*   labels  = (const int*)d_in[3];

  char* ws = (char*)d_ws;
  unsigned char* sf8 = (unsigned char*)ws;                        // 2 MiB fp8
  float* sq   = (float*)(ws + (size_t)NROWS * KDIM);              // 32 KiB
  float* accg = (float*)(ws + (size_t)NROWS * KDIM + NROWS * 4);  // 8 B
  float* out  = (float*)d_out;

  prep_kernel<<<NROWS, 128, 0, stream>>>(samples, sf8, sq, accg);
  pair_kernel<<<GRID, 512, 0, stream>>>(sf8, sq, labels, accg);
  finalize_kernel<<<1, 1, 0, stream>>>(accg, out);
}